// Round 1
// baseline (117.829 us; speedup 1.0000x reference)
//
#include <hip/hip_runtime.h>

// XTermFrequency: per-row histogram + normalize.
//   assignments: [B=512, S=8192] int32 in [0, V=50257)
//   out:         [B, V] float32 = counts / S   (row sum of counts == S exactly)
//
// Strategy: 1 block per row. Row (32 KB) loaded once into registers
// (32 int32/thread via int4). Vocab processed in 4 LDS chunks of 12800 bins
// (50 KB uint histogram each -> 3 blocks/CU LDS-wise; grid needs only 2/CU).
// Output written exactly once, coalesced. scale = 1/S is a power of two so
// all outputs are exact.

#define TF_BLOCK 256
#define TF_CHUNK 12800   // bins per LDS chunk (50 KB)
#define TF_NCHUNK 4      // 4 * 12800 = 51200 >= 50257
#define TF_VPT 32        // values per thread = S / TF_BLOCK (S = 8192)

__global__ __launch_bounds__(TF_BLOCK)
void XTermFrequency_hist_kernel(const int* __restrict__ assign,
                                float* __restrict__ out,
                                int V, int S, float scale) {
    __shared__ unsigned int hist[TF_CHUNK];
    const int row = blockIdx.x;
    const int tid = threadIdx.x;

    // Load this block's row into registers: 8 coalesced int4 loads per thread.
    const int4* rowp = (const int4*)(assign + (long long)row * S);
    int4 vals[TF_VPT / 4];
#pragma unroll
    for (int k = 0; k < TF_VPT / 4; ++k) {
        vals[k] = rowp[tid + k * TF_BLOCK];
    }

    float* __restrict__ orow = out + (long long)row * V;

    for (int c = 0; c < TF_NCHUNK; ++c) {
        const int base = c * TF_CHUNK;
        const int len = min(V - base, TF_CHUNK);

        // Zero the LDS histogram for this chunk.
        for (int i = tid; i < TF_CHUNK; i += TF_BLOCK) hist[i] = 0u;
        __syncthreads();

        // Scatter this thread's values into the chunk (range-checked).
#pragma unroll
        for (int k = 0; k < TF_VPT / 4; ++k) {
            const int4 v4 = vals[k];
            unsigned int d;
            d = (unsigned int)(v4.x - base);
            if (d < (unsigned int)TF_CHUNK) atomicAdd(&hist[d], 1u);
            d = (unsigned int)(v4.y - base);
            if (d < (unsigned int)TF_CHUNK) atomicAdd(&hist[d], 1u);
            d = (unsigned int)(v4.z - base);
            if (d < (unsigned int)TF_CHUNK) atomicAdd(&hist[d], 1u);
            d = (unsigned int)(v4.w - base);
            if (d < (unsigned int)TF_CHUNK) atomicAdd(&hist[d], 1u);
        }
        __syncthreads();

        // Coalesced write-out of normalized counts.
        for (int i = tid; i < len; i += TF_BLOCK) {
            orow[base + i] = (float)hist[i] * scale;
        }
        __syncthreads();  // protect hist from next chunk's zeroing
    }
}

extern "C" void kernel_launch(void* const* d_in, const int* in_sizes, int n_in,
                              void* d_out, int out_size, void* d_ws, size_t ws_size,
                              hipStream_t stream) {
    const int* assign = (const int*)d_in[0];
    float* out = (float*)d_out;

    // Known problem shape: V = 50257; derive B, S from sizes so the launch
    // stays consistent with the harness-provided buffers.
    const int V = 50257;
    const int B = out_size / V;          // 512
    const int S = in_sizes[0] / B;       // 8192
    const float scale = 1.0f / (float)S; // exact power of two

    XTermFrequency_hist_kernel<<<dim3(B), dim3(TF_BLOCK), 0, stream>>>(
        assign, out, V, S, scale);
}